// Round 7
// baseline (282.728 us; speedup 1.0000x reference)
//
#include <hip/hip_runtime.h>
#include <hip/hip_fp16.h>
#include <math.h>

// Problem constants
#define E     256
#define HW    1024               // 32*32
#define NTOK  8192               // B*H*W
#define NE    16384
// Screening margin: empirical f16-screen error class ~0.03-0.05 max; 0.5
// passed round 12 with absmax 0 (~10x headroom).
#define MARGIN 0.5f

typedef __attribute__((ext_vector_type(8))) _Float16 f16x8;
typedef __attribute__((ext_vector_type(4))) float    f32x4;

typedef __attribute__((address_space(3))) unsigned int       as3_u32;
typedef const __attribute__((address_space(1))) unsigned int as1_u32;

// async 16B/lane global->LDS: LDS dest = wave-uniform base + lane*16
static __device__ __forceinline__ void async_cp16(const void* g, void* l) {
    __builtin_amdgcn_global_load_lds((as1_u32*)g, (as3_u32*)l, 16, 0, 0);
}

// float -> order-preserving uint32 (no NaNs here)
__device__ __forceinline__ unsigned int f2key(float f) {
    unsigned int u = __float_as_uint(f);
    return (u & 0x80000000u) ? ~u : (u | 0x80000000u);
}
__device__ __forceinline__ float key2f(unsigned int k) {
    return __uint_as_float((k & 0x80000000u) ? (k ^ 0x80000000u) : ~k);
}
// merge sorted pair (a1,a2) into running (m1,m2): two smallest overall
__device__ __forceinline__ void kmin2(unsigned long long& m1, unsigned long long& m2,
                                      unsigned long long a1, unsigned long long a2) {
    unsigned long long lo = m1 < a1 ? m1 : a1;
    unsigned long long hi = m1 < a1 ? a1 : m1;
    unsigned long long s  = m2 < a2 ? m2 : a2;
    m1 = lo;
    m2 = hi < s ? hi : s;
}

// ---------------------------------------------------------------------------
// Kernel 1 (fused preps — one dispatch, branch on blockIdx).
// blocks [0,4096): codebook prep. Wave per row: cnorm[n] = sum(c^2) fp32,
//   B2h[n][k] = f16(c_k), K-contiguous (512 B rows).
// blocks [4096,4608): z prep with transpose. z[b][e][hw] fp32 ->
//   A2h[m=b*1024+hw][e] f16 via 64hw x 64e padded-LDS tile.
// ---------------------------------------------------------------------------
__global__ __launch_bounds__(256) void k_prep(const float* __restrict__ cb,
                                              const float* __restrict__ z,
                                              unsigned short* __restrict__ B2,
                                              unsigned short* __restrict__ A2,
                                              float* __restrict__ cnorm) {
    __shared__ float lds[64 * 65];
    const int tid = threadIdx.x;
    if (blockIdx.x < 4096) {
        const int wid  = tid >> 6;
        const int lane = tid & 63;
        const int row  = blockIdx.x * 4 + wid;
        float4 v = *(const float4*)(cb + (size_t)row * E + lane * 4);
        float s = v.x * v.x + v.y * v.y + v.z * v.z + v.w * v.w;
#pragma unroll
        for (int off = 32; off >= 1; off >>= 1) s += __shfl_xor(s, off, 64);
        if (lane == 0) cnorm[row] = s;

        ushort4 hi4 = {__half_as_ushort(__float2half(v.x)),
                       __half_as_ushort(__float2half(v.y)),
                       __half_as_ushort(__float2half(v.z)),
                       __half_as_ushort(__float2half(v.w))};
        *(ushort4*)(B2 + (size_t)row * E + lane * 4) = hi4;   // coalesced
    } else {
        const int t   = blockIdx.x - 4096;       // 0..511
        const int hw0 = (t & 15) * 64;
        const int e0  = ((t >> 4) & 3) * 64;
        const int b   = t >> 6;
#pragma unroll
        for (int r = 0; r < 16; ++r) {
            int e  = e0 + r * 4 + (tid >> 6);
            int hw = hw0 + (tid & 63);
            lds[(tid & 63) * 65 + r * 4 + (tid >> 6)] =
                z[((size_t)b * E + e) * HW + hw];
        }
        __syncthreads();
        const int row = tid & 63;          // hw within tile
        const int q   = tid >> 6;          // 16-col group
        const size_t m = (size_t)b * HW + hw0 + row;
        unsigned short* __restrict__ ph = A2 + m * E + e0 + q * 16;
#pragma unroll
        for (int g = 0; g < 4; ++g) {
            ushort4 h = {__half_as_ushort(__float2half(lds[row * 65 + q * 16 + g * 4 + 0])),
                         __half_as_ushort(__float2half(lds[row * 65 + q * 16 + g * 4 + 1])),
                         __half_as_ushort(__float2half(lds[row * 65 + q * 16 + g * 4 + 2])),
                         __half_as_ushort(__float2half(lds[row * 65 + q * 16 + g * 4 + 3]))};
            *(ushort4*)(ph + g * 4) = h;
        }
    }
}

// ---------------------------------------------------------------------------
// Kernel 2 (pass 1): hi.hi screening GEMM.
// ROUND 20: A-operand direct-from-global (LDS bypass). The r3 LDS budget
// (48 KB/pipe/K-step; pipe-bound ~58us of the 103) says cut LDS bytes.
// A-frag = 16B/lane at A2row(wm+i*16+l15) + kc*64 + (lane>>4)*16 — a
// 64B-segment coalesced load (4 lanes/row), chunk algebra identical to the
// old swizzled-LDS image. A goes global->reg (2-deep ping-pong, issued one
// K-step ahead: ~1.7k cy cover >> ~400 cy L2 latency; A2 = 4MB, L2-resident
// per XCD under the swizzle). B keeps the proven LDS path. LDS/K-step
// 48->28 KB. vmcnt: 6 issues/iter (4 A-reg + 2 B-stage); wait vmcnt(6)
// before the barrier covers A(kc)+B(kc) (in-order counter). VGPR ~154
// unified < 170 -> 3 blocks/CU retained (r4/r5 lesson: never trade TLP).
// Epilogue (shuffle-free scatter/gather, r3-proven) unchanged.
// ---------------------------------------------------------------------------
__global__ __launch_bounds__(256, 3) void k_mfma(
    const unsigned short* __restrict__ A2, const unsigned short* __restrict__ B2,
    const float* __restrict__ cnorm,
    unsigned long long* __restrict__ rec1, unsigned int* __restrict__ rec2)
{
    // pool layout:
    //   main loop : Bh bufs [0,16384)   (A is LDS-bypassed)
    //   epilogue  : K1 u64[32][128] swz [0,32768)
    //               V2 u32[32][128] swz [32768,49152)
    //               R1 u64[128]         [49152,50176)
    //               R2 u32[128]         [50176,50688)
    __shared__ __align__(16) char pool[50688];

    const int tid  = threadIdx.x;
    const int lane = tid & 63;
    const int wave = __builtin_amdgcn_readfirstlane(tid >> 6);

    const int bid   = blockIdx.x;
    const int xcd   = bid & 7;
    const int loc   = bid >> 3;
    const int xtile = loc >> 4;                // 0..63 token tile (slowest)
    const int ytile = xcd * 16 + (loc & 15);   // 0..127 code chunk
    const int m0 = xtile * 128;
    const int n0 = ytile * 128;

    const int wm = (wave >> 1) * 64;
    const int wn = (wave & 1) * 64;

    const int srow  = (lane >> 2);                              // 0..15
    const int schnk = (((lane & 3) ^ ((lane >> 3) & 3)) * 16);  // swizzled src chunk
    const int l15   = lane & 15;

    char* BhB = pool;              // [2][8192 B]

    f32x4 acc1[4][4];
#pragma unroll
    for (int i = 0; i < 4; ++i)
#pragma unroll
        for (int j = 0; j < 4; ++j) acc1[i][j] = (f32x4){0.f, 0.f, 0.f, 0.f};

    const int pofs = (((lane >> 4) ^ ((lane >> 1) & 3)) << 4);

    // A-direct per-lane base: row m0+wm+l15, k-chunk (lane>>4)*16 bytes
    const char* pab = (const char*)A2 + (size_t)(m0 + wm + l15) * 512
                      + ((lane >> 4) << 4);

    // B staging (per wave: 2 async ops per K-step, rows [w*32, w*32+32))
    const size_t brow0 = (size_t)(n0 + wave * 32 + srow) * 512 + schnk;
    const size_t dof0  = (size_t)(wave * 2048);

#define STAGE_B(buf, kc)                                                      \
    do {                                                                      \
        const int kb_ = (kc) * 64;                                            \
        async_cp16((const char*)B2 + brow0 + kb_,        BhB + (buf) * 8192 + dof0);        \
        async_cp16((const char*)B2 + brow0 + 8192 + kb_, BhB + (buf) * 8192 + dof0 + 1024); \
    } while (0)

    f16x8 ahb[2][4];
    // prologue: A(0) into regs, B(0) into LDS buf0 — 6 ops outstanding
#pragma unroll
    for (int i = 0; i < 4; ++i)
        ahb[0][i] = *(const f16x8*)(pab + i * 8192);
    STAGE_B(0, 0);

#pragma unroll
    for (int kc = 0; kc < 8; ++kc) {
        const int cur = kc & 1;
        if (kc < 7) {
            // issue A(kc+1) reg loads + B(kc+1) stage: 6 new ops
#pragma unroll
            for (int i = 0; i < 4; ++i)
                ahb[cur ^ 1][i] =
                    *(const f16x8*)(pab + i * 8192 + (kc + 1) * 64);
            STAGE_B(cur ^ 1, kc + 1);
            // oldest 6 = A(kc)+B(kc): regs valid, staged B in LDS; barrier
            // makes B(kc) globally visible. Next tile's 6 stay in flight.
            asm volatile("s_waitcnt vmcnt(6)\n\ts_barrier" ::: "memory");
        } else {
            asm volatile("s_waitcnt vmcnt(0)\n\ts_barrier" ::: "memory");
        }
        f16x8 bh[4];
#pragma unroll
        for (int j = 0; j < 4; ++j)
            bh[j] = *(const f16x8*)(BhB + cur * 8192 +
                    (wn + j * 16 + l15) * 64 + pofs);
        __builtin_amdgcn_s_setprio(1);
#pragma unroll
        for (int i = 0; i < 4; ++i)
#pragma unroll
            for (int j = 0; j < 4; ++j)
                acc1[i][j] = __builtin_amdgcn_mfma_f32_16x16x32_f16(
                    ahb[cur][i], bh[j], acc1[i][j], 0, 0, 0);
        __builtin_amdgcn_s_setprio(0);
        // all waves done reading buf(kc) before it is restaged; after the
        // LAST iter this also guards the epilogue pool overlay.
        asm volatile("s_barrier" ::: "memory");
    }
#undef STAGE_B

    // ---- epilogue phase 1: local 4->2 two-min (VALU), LDS scatter ---------
    unsigned long long* K1 = (unsigned long long*)pool;        // [32][128] swz
    unsigned int*       V2 = (unsigned int*)(pool + 32768);    // [32][128] swz
    unsigned long long* R1 = (unsigned long long*)(pool + 49152);
    unsigned int*       R2 = (unsigned int*)(pool + 50176);

    const int nb = n0 + wn + l15;               // lane's col base
    float cn[4];
#pragma unroll
    for (int j = 0; j < 4; ++j) cn[j] = cnorm[nb + j * 16];

    const int g = (wave & 1) * 16 + l15;        // 0..31 column group
    char* k1base = (char*)K1 + g * 1024;
    char* v2base = (char*)V2 + g * 512;
    const int gx3 = (g & 15) << 3;   // K1 XOR swizzle (byte bits 3-6)
    const int gx2 = (g & 15) << 2;   // V2 XOR swizzle (byte bits 2-5)

#pragma unroll
    for (int i = 0; i < 4; ++i) {
#pragma unroll
        for (int r = 0; r < 4; ++r) {
            float d0 = fmaf(-2.f, acc1[i][0][r], cn[0]);
            float d1 = fmaf(-2.f, acc1[i][1][r], cn[1]);
            float d2 = fmaf(-2.f, acc1[i][2][r], cn[2]);
            float d3 = fmaf(-2.f, acc1[i][3][r], cn[3]);
            float m01 = fminf(d0, d1), M01 = fmaxf(d0, d1);
            float m23 = fminf(d2, d3), M23 = fmaxf(d2, d3);
            float v1 = fminf(m01, m23);
            float v2 = fminf(fminf(M01, M23), fmaxf(m01, m23));
            // argmin among the 4 local cols (descending j keeps smallest n)
            int cand = 0x7fffffff;
            if (d3 == v1) cand = nb + 48;
            if (d2 == v1) cand = nb + 32;
            if (d1 == v1) cand = nb + 16;
            if (d0 == v1) cand = nb;
            const int rowl = wm + i * 16 + ((lane >> 4) << 2) + r;  // 0..127
            *(unsigned long long*)(k1base + ((rowl * 8) ^ gx3)) =
                ((unsigned long long)f2key(v1) << 32) | (unsigned int)cand;
            *(unsigned int*)(v2base + ((rowl * 4) ^ gx2)) = f2key(v2);
        }
    }
    __syncthreads();

    // ---- epilogue phase 2: per (row, half) serial gather + u64-min --------
    {
        const int rowl = tid & 127;
        const int hsel = tid >> 7;              // 0: groups 0-15, 1: 16-31
        unsigned long long m1 = ~0ull;
        unsigned int k2 = 0xffffffffu;
#pragma unroll
        for (int gg = 0; gg < 16; ++gg) {
            const int gi = hsel * 16 + gg;
            unsigned long long a1 = *(const unsigned long long*)
                ((const char*)K1 + gi * 1024 + ((rowl * 8) ^ ((gi & 15) << 3)));
            unsigned int a2 = *(const unsigned int*)
                ((const char*)V2 + gi * 512 + ((rowl * 4) ^ ((gi & 15) << 2)));
            unsigned int m1k = (unsigned int)(m1 >> 32);
            unsigned int a1k = (unsigned int)(a1 >> 32);
            unsigned int hi  = (m1 < a1) ? a1k : m1k;   // loser of top compare
            k2 = min(min(k2, a2), hi);
            m1 = m1 < a1 ? m1 : a1;
        }
        if (hsel) { R1[rowl] = m1; R2[rowl] = k2; }
        __syncthreads();
        if (!hsel) {
            unsigned long long a1 = R1[rowl];
            unsigned int a2 = R2[rowl];
            unsigned int m1k = (unsigned int)(m1 >> 32);
            unsigned int a1k = (unsigned int)(a1 >> 32);
            unsigned int hi  = (m1 < a1) ? a1k : m1k;
            k2 = min(min(k2, a2), hi);
            m1 = m1 < a1 ? m1 : a1;
            rec1[(size_t)(m0 + rowl) * 128 + ytile] = m1;
            rec2[(size_t)(m0 + rowl) * 128 + ytile] = k2;
        }
    }
}

// ---------------------------------------------------------------------------
// Kernel 3 (pass 2, k_out fused in). Wave per token: reduce 128 chunk
// records to (best, 2nd); certified if 2nd >= best + MARGIN, else exact
// fp32 rescore of under-threshold chunks. Then the block's 4 tokens (same
// b, consecutive hw) write out cooperatively with exact x + (xq - x) f32
// arithmetic.
// ---------------------------------------------------------------------------
__global__ __launch_bounds__(256) void k_pick(
    const unsigned long long* __restrict__ rec1, const unsigned int* __restrict__ rec2,
    const float* __restrict__ z, const float* __restrict__ cb,
    const float* __restrict__ cnorm, float* __restrict__ out)
{
    __shared__ float ldsx[4 * 256];             // per-wave x slice
    __shared__ int   codes[4];
    const int lane  = threadIdx.x & 63;
    const int wid   = threadIdx.x >> 6;
    const int token = blockIdx.x * 4 + wid;
    const int b  = token >> 10, hw = token & 1023;

    unsigned long long cm0 = rec1[(size_t)token * 128 + lane];        // coalesced
    unsigned long long cm1 = rec1[(size_t)token * 128 + 64 + lane];
    unsigned long long s0  = ((unsigned long long)rec2[(size_t)token * 128 + lane] << 32)
                             | 0xffffffffull;
    unsigned long long s1  = ((unsigned long long)rec2[(size_t)token * 128 + 64 + lane] << 32)
                             | 0xffffffffull;

    unsigned long long m1 = cm0, m2 = s0;
    kmin2(m1, m2, cm1, s1);
#pragma unroll
    for (int off = 1; off < 64; off <<= 1) {
        unsigned long long o1 = __shfl_xor(m1, off, 64);
        unsigned long long o2 = __shfl_xor(m2, off, 64);
        kmin2(m1, m2, o1, o2);
    }
    float d1 = key2f((unsigned int)(m1 >> 32));
    float d2 = key2f((unsigned int)(m2 >> 32));
    unsigned long long final;
    if (d2 >= d1 + MARGIN) {                 // certified
        final = m1;
    } else {
        // ---- exact fp32 rescore, lane-per-code ----------------------------
        const float thr = d1 + MARGIN;
        float* xs = ldsx + wid * 256;
        {
            const float* zp = z + (size_t)b * (E * HW) + hw;
            float4 xv;
            xv.x = zp[(size_t)(lane * 4 + 0) * HW];
            xv.y = zp[(size_t)(lane * 4 + 1) * HW];
            xv.z = zp[(size_t)(lane * 4 + 2) * HW];
            xv.w = zp[(size_t)(lane * 4 + 3) * HW];
            *(float4*)&xs[lane * 4] = xv;
        }
        unsigned long long msk0 = __ballot(key2f((unsigned int)(cm0 >> 32)) < thr);
        unsigned long long msk1 = __ballot(key2f((unsigned int)(cm1 >> 32)) < thr);

        unsigned long long best = ~0ull;
        while (msk0 | msk1) {
            int c;
            if (msk0) { c = __builtin_ctzll(msk0); msk0 &= msk0 - 1; }
            else      { c = 64 + __builtin_ctzll(msk1); msk1 &= msk1 - 1; }
            const int na = c * 128 + lane;          // lane's two codes
            const int nbr = na + 64;
            const float* ca  = cb + (size_t)na * E;
            const float* cbp = cb + (size_t)nbr * E;
            float a0 = 0.f, a1 = 0.f, a2 = 0.f, a3 = 0.f;
            float b0 = 0.f, b1 = 0.f, b2 = 0.f, b3 = 0.f;
#pragma unroll 8
            for (int kg = 0; kg < 64; ++kg) {
                float4 xv = *(const float4*)&xs[kg * 4];   // wave-uniform broadcast
                float4 va = *(const float4*)(ca  + kg * 4);
                float4 vb = *(const float4*)(cbp + kg * 4);
                a0 = fmaf(xv.x, va.x, a0); a1 = fmaf(xv.y, va.y, a1);
                a2 = fmaf(xv.z, va.z, a2); a3 = fmaf(xv.w, va.w, a3);
                b0 = fmaf(xv.x, vb.x, b0); b1 = fmaf(xv.y, vb.y, b1);
                b2 = fmaf(xv.z, vb.z, b2); b3 = fmaf(xv.w, vb.w, b3);
            }
            float da = fmaf(-2.f, (a0 + a1) + (a2 + a3), cnorm[na]);
            float db = fmaf(-2.f, (b0 + b1) + (b2 + b3), cnorm[nbr]);
            unsigned long long ka =
                ((unsigned long long)f2key(da) << 32) | (unsigned int)na;
            unsigned long long kb2 =
                ((unsigned long long)f2key(db) << 32) | (unsigned int)nbr;
            best = ka < best ? ka : best;
            best = kb2 < best ? kb2 : best;
        }
#pragma unroll
        for (int off = 1; off < 64; off <<= 1) {
            unsigned long long o = __shfl_xor(best, off, 64);
            best = o < best ? o : best;
        }
        final = best;
    }
    if (lane == 0) codes[wid] = (int)(final & 0xffffffffull);
    __syncthreads();

    // ---- fused out epilogue: 4 tokens (same b, hw0..hw0+3) ----------------
    {
        const int t   = threadIdx.x;               // e index
        const int bb  = (blockIdx.x * 4) >> 10;
        const int hw0 = (blockIdx.x * 4) & 1023;
        const int c0 = codes[0], c1 = codes[1], c2 = codes[2], c3 = codes[3];
        const size_t o = ((size_t)bb * E + t) * HW + hw0;
        float4 x = *(const float4*)(z + o);
        float q0 = cb[(size_t)c0 * E + t];
        float q1 = cb[(size_t)c1 * E + t];
        float q2 = cb[(size_t)c2 * E + t];
        float q3 = cb[(size_t)c3 * E + t];
        float4 w;
        w.x = x.x + (q0 - x.x);
        w.y = x.y + (q1 - x.y);
        w.z = x.z + (q2 - x.z);
        w.w = x.w + (q3 - x.w);
        *(float4*)(out + o) = w;
    }
}

// ---------------------------------------------------------------------------
extern "C" void kernel_launch(void* const* d_in, const int* in_sizes, int n_in,
                              void* d_out, int out_size, void* d_ws, size_t ws_size,
                              hipStream_t stream) {
    const float* z  = (const float*)d_in[0];    // [8,256,32,32]
    const float* cb = (const float*)d_in[1];    // [16384,256]
    float* out = (float*)d_out;

    // workspace layout (bytes):
    //   A2h : 8192*256*2   = 4 MB  @ 0
    //   B2h : 16384*256*2  = 8 MB  @ 4M
    //   rec1: 8192*128*8   = 8 MB  @ 12M   ([token][chunk])
    //   rec2: 8192*128*4   = 4 MB  @ 20M   ([token][chunk])
    //   cnorm: 64 KB               @ 24M   (total ~24.06 MB)
    char* ws = (char*)d_ws;
    unsigned short* A2 = (unsigned short*)ws;
    unsigned short* B2 = (unsigned short*)(ws + (size_t)4 * 1024 * 1024);
    unsigned long long* rec1 = (unsigned long long*)(ws + (size_t)12 * 1024 * 1024);
    unsigned int* rec2 = (unsigned int*)(ws + (size_t)20 * 1024 * 1024);
    float* cnorm = (float*)(ws + (size_t)24 * 1024 * 1024);

    k_prep <<<4608, 256, 0, stream>>>(cb, z, B2, A2, cnorm);
    k_mfma <<<8192, 256, 0, stream>>>(A2, B2, cnorm, rec1, rec2);
    k_pick <<<NTOK / 4, 256, 0, stream>>>(rec1, rec2, z, cb, cnorm, out);
}

// Round 9
// 228.987 us; speedup vs baseline: 1.2347x; 1.2347x over previous
//
#include <hip/hip_runtime.h>
#include <hip/hip_fp16.h>
#include <math.h>

// Problem constants
#define E     256
#define HW    1024               // 32*32
#define NTOK  8192               // B*H*W
#define NE    16384
// Screening margin: empirical f16-screen error class ~0.03-0.05 max; 0.5
// passed round 12 with absmax 0 (~10x headroom).
#define MARGIN 0.5f

typedef __attribute__((ext_vector_type(8))) _Float16 f16x8;
typedef __attribute__((ext_vector_type(4))) float    f32x4;

typedef __attribute__((address_space(3))) unsigned int       as3_u32;
typedef const __attribute__((address_space(1))) unsigned int as1_u32;

// async 16B/lane global->LDS: LDS dest = wave-uniform base + lane*16
static __device__ __forceinline__ void async_cp16(const void* g, void* l) {
    __builtin_amdgcn_global_load_lds((as1_u32*)g, (as3_u32*)l, 16, 0, 0);
}

// float -> order-preserving uint32 (no NaNs here)
__device__ __forceinline__ unsigned int f2key(float f) {
    unsigned int u = __float_as_uint(f);
    return (u & 0x80000000u) ? ~u : (u | 0x80000000u);
}
__device__ __forceinline__ float key2f(unsigned int k) {
    return __uint_as_float((k & 0x80000000u) ? (k ^ 0x80000000u) : ~k);
}
// merge sorted pair (a1,a2) into running (m1,m2): two smallest overall
__device__ __forceinline__ void kmin2(unsigned long long& m1, unsigned long long& m2,
                                      unsigned long long a1, unsigned long long a2) {
    unsigned long long lo = m1 < a1 ? m1 : a1;
    unsigned long long hi = m1 < a1 ? a1 : m1;
    unsigned long long s  = m2 < a2 ? m2 : a2;
    m1 = lo;
    m2 = hi < s ? hi : s;
}

// ---------------------------------------------------------------------------
// ROUND 21 packed chunk record (u64):
//   [63:32] v1key (exact)  [31:18] cand (14b, NE=16384)  [17:0] v2key>>14
// v2 truncated DOWN = conservative (extra rescores possible, never a wrong
// certification). Unpack clamps v2rec = max((r&0x3ffff)<<14, v1key) so a
// truncated v2 can never undercut its own chunk's v1 and win the argmin.
// u64-min orders by v1key then smallest cand (ties) — matches jnp.argmin.
// ---------------------------------------------------------------------------

// ---------------------------------------------------------------------------
// Kernel 1 (fused preps — one dispatch, branch on blockIdx).
// ---------------------------------------------------------------------------
__global__ __launch_bounds__(256) void k_prep(const float* __restrict__ cb,
                                              const float* __restrict__ z,
                                              unsigned short* __restrict__ B2,
                                              unsigned short* __restrict__ A2,
                                              float* __restrict__ cnorm) {
    __shared__ float lds[64 * 65];
    const int tid = threadIdx.x;
    if (blockIdx.x < 4096) {
        const int wid  = tid >> 6;
        const int lane = tid & 63;
        const int row  = blockIdx.x * 4 + wid;
        float4 v = *(const float4*)(cb + (size_t)row * E + lane * 4);
        float s = v.x * v.x + v.y * v.y + v.z * v.z + v.w * v.w;
#pragma unroll
        for (int off = 32; off >= 1; off >>= 1) s += __shfl_xor(s, off, 64);
        if (lane == 0) cnorm[row] = s;

        ushort4 hi4 = {__half_as_ushort(__float2half(v.x)),
                       __half_as_ushort(__float2half(v.y)),
                       __half_as_ushort(__float2half(v.z)),
                       __half_as_ushort(__float2half(v.w))};
        *(ushort4*)(B2 + (size_t)row * E + lane * 4) = hi4;   // coalesced
    } else {
        const int t   = blockIdx.x - 4096;       // 0..511
        const int hw0 = (t & 15) * 64;
        const int e0  = ((t >> 4) & 3) * 64;
        const int b   = t >> 6;
#pragma unroll
        for (int r = 0; r < 16; ++r) {
            int e  = e0 + r * 4 + (tid >> 6);
            int hw = hw0 + (tid & 63);
            lds[(tid & 63) * 65 + r * 4 + (tid >> 6)] =
                z[((size_t)b * E + e) * HW + hw];
        }
        __syncthreads();
        const int row = tid & 63;          // hw within tile
        const int q   = tid >> 6;          // 16-col group
        const size_t m = (size_t)b * HW + hw0 + row;
        unsigned short* __restrict__ ph = A2 + m * E + e0 + q * 16;
#pragma unroll
        for (int g = 0; g < 4; ++g) {
            ushort4 h = {__half_as_ushort(__float2half(lds[row * 65 + q * 16 + g * 4 + 0])),
                         __half_as_ushort(__float2half(lds[row * 65 + q * 16 + g * 4 + 1])),
                         __half_as_ushort(__float2half(lds[row * 65 + q * 16 + g * 4 + 2])),
                         __half_as_ushort(__float2half(lds[row * 65 + q * 16 + g * 4 + 3]))};
            *(ushort4*)(ph + g * 4) = h;
        }
    }
}

// ---------------------------------------------------------------------------
// Kernel 2 (pass 1): hi.hi screening GEMM. Main loop = r6/r3 proven 128^2,
// 3 blocks/CU, 2-phase dbuf global_load_lds, counted vmcnt(4), setprio
// (103us, absmax 0). ROUND 21: packed-u64 epilogue — scatter/gather ds ops
// halved (b64 only), rec2 eliminated, LDS pool 50.7->34.3 KB.
// r7 lesson kept in comments: per-lane A-direct-to-reg regressed +55% (the
// compiler's waitcnt pass drains in-flight loads before each MFMA when it
// can't prove the inline vmcnt covers the reg dependency).
// ---------------------------------------------------------------------------
__global__ __launch_bounds__(256, 3) void k_mfma(
    const unsigned short* __restrict__ A2, const unsigned short* __restrict__ B2,
    const float* __restrict__ cnorm, unsigned long long* __restrict__ rec)
{
    // pool layout:
    //   main loop : Ah bufs [0,16384), Bh bufs [16384,32768)
    //   epilogue  : K1 u64[32][128] swz [0,32768)
    //               R1 u64[128]         [32768,33792)
    //               R2 u32[128]         [33792,34304)
    __shared__ __align__(16) char pool[34304];

    const int tid  = threadIdx.x;
    const int lane = tid & 63;
    const int wave = __builtin_amdgcn_readfirstlane(tid >> 6);

    const int bid   = blockIdx.x;
    const int xcd   = bid & 7;
    const int loc   = bid >> 3;
    const int xtile = loc >> 4;                // 0..63 token tile (slowest)
    const int ytile = xcd * 16 + (loc & 15);   // 0..127 code chunk
    const int m0 = xtile * 128;
    const int n0 = ytile * 128;

    const int wm = (wave >> 1) * 64;
    const int wn = (wave & 1) * 64;

    const int srow  = (lane >> 2);                              // 0..15
    const int schnk = (((lane & 3) ^ ((lane >> 3) & 3)) * 16);  // swizzled src chunk
    const int l15   = lane & 15;

    char* AhB = pool;              // [2][8192 B]
    char* BhB = pool + 16384;      // [2][8192 B]

    f32x4 acc1[4][4];
#pragma unroll
    for (int i = 0; i < 4; ++i)
#pragma unroll
        for (int j = 0; j < 4; ++j) acc1[i][j] = (f32x4){0.f, 0.f, 0.f, 0.f};

    const int pofs = (((lane >> 4) ^ ((lane >> 1) & 3)) << 4);

    // per-wave source/dest staging offsets (4 async ops per wave per stage)
    const size_t arow0 = (size_t)(m0 + wave * 32 + srow) * 512 + schnk;
    const size_t brow0 = (size_t)(n0 + wave * 32 + srow) * 512 + schnk;
    const size_t dof0  = (size_t)(wave * 2048);

    // STAGE(buf, kc): issue 4 per-wave global_load_lds (A,B,A,B)
#define STAGE(buf, kc)                                                        \
    do {                                                                      \
        const int kb_ = (kc) * 64;                                            \
        async_cp16((const char*)A2 + arow0 + kb_,        AhB + (buf) * 8192 + dof0);        \
        async_cp16((const char*)B2 + brow0 + kb_,        BhB + (buf) * 8192 + dof0);        \
        async_cp16((const char*)A2 + arow0 + 8192 + kb_, AhB + (buf) * 8192 + dof0 + 1024); \
        async_cp16((const char*)B2 + brow0 + 8192 + kb_, BhB + (buf) * 8192 + dof0 + 1024); \
    } while (0)

    STAGE(0, 0);
    int cur = 0;
    for (int kc = 0; kc < 8; ++kc) {
        if (kc < 7) {
            STAGE(cur ^ 1, kc + 1);
            // drain only the oldest 4 (cur buf); next buf's 4 stay in flight
            asm volatile("s_waitcnt vmcnt(4)\n\ts_barrier" ::: "memory");
        } else {
            asm volatile("s_waitcnt vmcnt(0)\n\ts_barrier" ::: "memory");
        }
        f16x8 ah[4], bh[4];
#pragma unroll
        for (int i = 0; i < 4; ++i)
            ah[i] = *(const f16x8*)(AhB + cur * 8192 +
                    (wm + i * 16 + l15) * 64 + pofs);
#pragma unroll
        for (int j = 0; j < 4; ++j)
            bh[j] = *(const f16x8*)(BhB + cur * 8192 +
                    (wn + j * 16 + l15) * 64 + pofs);
        __builtin_amdgcn_s_setprio(1);
#pragma unroll
        for (int i = 0; i < 4; ++i)
#pragma unroll
            for (int j = 0; j < 4; ++j)
                acc1[i][j] = __builtin_amdgcn_mfma_f32_16x16x32_f16(
                    ah[i], bh[j], acc1[i][j], 0, 0, 0);
        __builtin_amdgcn_s_setprio(0);
        // all waves done reading cur before it is overwritten next iter;
        // after the LAST iter this also guards the epilogue pool overlay.
        asm volatile("s_barrier" ::: "memory");
        cur ^= 1;
    }
#undef STAGE

    // ---- epilogue phase 1: local 4->2 two-min (VALU), packed b64 scatter --
    unsigned long long* R1 = (unsigned long long*)(pool + 32768);
    unsigned int*       R2 = (unsigned int*)(pool + 33792);

    const int nb = n0 + wn + l15;               // lane's col base
    float cn[4];
#pragma unroll
    for (int j = 0; j < 4; ++j) cn[j] = cnorm[nb + j * 16];

    const int g = (wave & 1) * 16 + l15;        // 0..31 column group
    char* k1base = pool + g * 1024;
    const int gx3 = l15 << 3;                   // K1 XOR swizzle (byte bits 3-6)

#pragma unroll
    for (int i = 0; i < 4; ++i) {
#pragma unroll
        for (int r = 0; r < 4; ++r) {
            float d0 = fmaf(-2.f, acc1[i][0][r], cn[0]);
            float d1 = fmaf(-2.f, acc1[i][1][r], cn[1]);
            float d2 = fmaf(-2.f, acc1[i][2][r], cn[2]);
            float d3 = fmaf(-2.f, acc1[i][3][r], cn[3]);
            float m01 = fminf(d0, d1), M01 = fmaxf(d0, d1);
            float m23 = fminf(d2, d3), M23 = fmaxf(d2, d3);
            float v1 = fminf(m01, m23);
            float v2 = fminf(fminf(M01, M23), fmaxf(m01, m23));
            // argmin among the 4 local cols (descending j keeps smallest n)
            int cand = 0x3fff;
            if (d3 == v1) cand = nb + 48;
            if (d2 == v1) cand = nb + 32;
            if (d1 == v1) cand = nb + 16;
            if (d0 == v1) cand = nb;
            const int rowl = wm + i * 16 + ((lane >> 4) << 2) + r;  // 0..127
            unsigned long long pk =
                ((unsigned long long)f2key(v1) << 32) |
                ((unsigned long long)(unsigned int)cand << 18) |
                (unsigned long long)(f2key(v2) >> 14);
            *(unsigned long long*)(k1base + ((rowl * 8) ^ gx3)) = pk;
        }
    }
    __syncthreads();

    // ---- epilogue phase 2: per (row, half) gather + two-min merge ---------
    {
        const int rowl = tid & 127;
        const int hsel = tid >> 7;              // 0: groups 0-15, 1: 16-31
        unsigned long long m1 = ~0ull;
        unsigned int k2 = 0xffffffffu;
#pragma unroll
        for (int gg = 0; gg < 16; ++gg) {
            const int gi = hsel * 16 + gg;
            unsigned long long a1 = *(const unsigned long long*)
                (pool + gi * 1024 + ((rowl * 8) ^ ((gi & 15) << 3)));
            unsigned int a1k = (unsigned int)(a1 >> 32);
            unsigned int v2r = (unsigned int)((a1 & 0x3ffffull) << 14);
            v2r = v2r > a1k ? v2r : a1k;        // clamp: lower bound, >= own v1
            unsigned int m1k = (unsigned int)(m1 >> 32);
            unsigned int lsr = (m1 < a1) ? a1k : m1k;   // loser of top compare
            k2 = min(min(k2, v2r), lsr);
            m1 = m1 < a1 ? m1 : a1;
        }
        if (hsel) { R1[rowl] = m1; R2[rowl] = k2; }
        __syncthreads();
        if (!hsel) {
            unsigned long long a1 = R1[rowl];
            unsigned int a2 = R2[rowl];
            unsigned int m1k = (unsigned int)(m1 >> 32);
            unsigned int a1k = (unsigned int)(a1 >> 32);
            unsigned int lsr = (m1 < a1) ? a1k : m1k;
            k2 = min(min(k2, a2), lsr);
            m1 = m1 < a1 ? m1 : a1;
            // rebuild record: winner's v1key+cand, merged v2 (trunc down)
            rec[(size_t)(m0 + rowl) * 128 + ytile] =
                (m1 & 0xfffffffffffc0000ull) | (unsigned long long)(k2 >> 14);
        }
    }
}

// ---------------------------------------------------------------------------
// Kernel 3 (pass 2, k_out fused). Wave per token: reduce 128 packed chunk
// records to (best, 2nd-bound); certified if 2nd >= best + MARGIN, else
// exact fp32 rescore of under-threshold chunks. Then the block's 4 tokens
// write out cooperatively with exact x + (xq - x) f32 arithmetic.
// ---------------------------------------------------------------------------
__global__ __launch_bounds__(256) void k_pick(
    const unsigned long long* __restrict__ rec,
    const float* __restrict__ z, const float* __restrict__ cb,
    const float* __restrict__ cnorm, float* __restrict__ out)
{
    __shared__ float ldsx[4 * 256];             // per-wave x slice
    __shared__ int   codes[4];
    const int lane  = threadIdx.x & 63;
    const int wid   = threadIdx.x >> 6;
    const int token = blockIdx.x * 4 + wid;
    const int b  = token >> 10, hw = token & 1023;

    unsigned long long r0 = rec[(size_t)token * 128 + lane];        // coalesced
    unsigned long long r1 = rec[(size_t)token * 128 + 64 + lane];
    unsigned int v1k0 = (unsigned int)(r0 >> 32);
    unsigned int v1k1 = (unsigned int)(r1 >> 32);
    unsigned int v2r0 = (unsigned int)((r0 & 0x3ffffull) << 14);
    unsigned int v2r1 = (unsigned int)((r1 & 0x3ffffull) << 14);
    v2r0 = v2r0 > v1k0 ? v2r0 : v1k0;           // clamp (see pack comment)
    v2r1 = v2r1 > v1k1 ? v2r1 : v1k1;
    unsigned long long s0 = ((unsigned long long)v2r0 << 32) | 0xffffffffull;
    unsigned long long s1 = ((unsigned long long)v2r1 << 32) | 0xffffffffull;

    unsigned long long m1 = r0, m2 = s0;
    kmin2(m1, m2, r1, s1);
#pragma unroll
    for (int off = 1; off < 64; off <<= 1) {
        unsigned long long o1 = __shfl_xor(m1, off, 64);
        unsigned long long o2 = __shfl_xor(m2, off, 64);
        kmin2(m1, m2, o1, o2);
    }
    float d1 = key2f((unsigned int)(m1 >> 32));
    float d2 = key2f((unsigned int)(m2 >> 32));
    int code;
    if (d2 >= d1 + MARGIN) {                 // certified
        code = (int)((m1 >> 18) & 0x3fffull);
    } else {
        // ---- exact fp32 rescore, lane-per-code ----------------------------
        const float thr = d1 + MARGIN;
        float* xs = ldsx + wid * 256;
        {
            const float* zp = z + (size_t)b * (E * HW) + hw;
            float4 xv;
            xv.x = zp[(size_t)(lane * 4 + 0) * HW];
            xv.y = zp[(size_t)(lane * 4 + 1) * HW];
            xv.z = zp[(size_t)(lane * 4 + 2) * HW];
            xv.w = zp[(size_t)(lane * 4 + 3) * HW];
            *(float4*)&xs[lane * 4] = xv;
        }
        unsigned long long msk0 = __ballot(key2f(v1k0) < thr);
        unsigned long long msk1 = __ballot(key2f(v1k1) < thr);

        unsigned long long best = ~0ull;
        while (msk0 | msk1) {
            int c;
            if (msk0) { c = __builtin_ctzll(msk0); msk0 &= msk0 - 1; }
            else      { c = 64 + __builtin_ctzll(msk1); msk1 &= msk1 - 1; }
            const int na = c * 128 + lane;          // lane's two codes
            const int nbr = na + 64;
            const float* ca  = cb + (size_t)na * E;
            const float* cbp = cb + (size_t)nbr * E;
            float a0 = 0.f, a1 = 0.f, a2 = 0.f, a3 = 0.f;
            float b0 = 0.f, b1 = 0.f, b2 = 0.f, b3 = 0.f;
#pragma unroll 8
            for (int kg = 0; kg < 64; ++kg) {
                float4 xv = *(const float4*)&xs[kg * 4];   // wave-uniform broadcast
                float4 va = *(const float4*)(ca  + kg * 4);
                float4 vb = *(const float4*)(cbp + kg * 4);
                a0 = fmaf(xv.x, va.x, a0); a1 = fmaf(xv.y, va.y, a1);
                a2 = fmaf(xv.z, va.z, a2); a3 = fmaf(xv.w, va.w, a3);
                b0 = fmaf(xv.x, vb.x, b0); b1 = fmaf(xv.y, vb.y, b1);
                b2 = fmaf(xv.z, vb.z, b2); b3 = fmaf(xv.w, vb.w, b3);
            }
            float da = fmaf(-2.f, (a0 + a1) + (a2 + a3), cnorm[na]);
            float db = fmaf(-2.f, (b0 + b1) + (b2 + b3), cnorm[nbr]);
            unsigned long long ka =
                ((unsigned long long)f2key(da) << 32) | (unsigned int)na;
            unsigned long long kb2 =
                ((unsigned long long)f2key(db) << 32) | (unsigned int)nbr;
            best = ka < best ? ka : best;
            best = kb2 < best ? kb2 : best;
        }
#pragma unroll
        for (int off = 1; off < 64; off <<= 1) {
            unsigned long long o = __shfl_xor(best, off, 64);
            best = o < best ? o : best;
        }
        code = (int)(best & 0xffffffffull);
    }
    if (lane == 0) codes[wid] = code;
    __syncthreads();

    // ---- fused out epilogue: 4 tokens (same b, hw0..hw0+3) ----------------
    {
        const int t   = threadIdx.x;               // e index
        const int bb  = (blockIdx.x * 4) >> 10;
        const int hw0 = (blockIdx.x * 4) & 1023;
        const int c0 = codes[0], c1 = codes[1], c2 = codes[2], c3 = codes[3];
        const size_t o = ((size_t)bb * E + t) * HW + hw0;
        float4 x = *(const float4*)(z + o);
        float q0 = cb[(size_t)c0 * E + t];
        float q1 = cb[(size_t)c1 * E + t];
        float q2 = cb[(size_t)c2 * E + t];
        float q3 = cb[(size_t)c3 * E + t];
        float4 w;
        w.x = x.x + (q0 - x.x);
        w.y = x.y + (q1 - x.y);
        w.z = x.z + (q2 - x.z);
        w.w = x.w + (q3 - x.w);
        *(float4*)(out + o) = w;
    }
}

// ---------------------------------------------------------------------------
extern "C" void kernel_launch(void* const* d_in, const int* in_sizes, int n_in,
                              void* d_out, int out_size, void* d_ws, size_t ws_size,
                              hipStream_t stream) {
    const float* z  = (const float*)d_in[0];    // [8,256,32,32]
    const float* cb = (const float*)d_in[1];    // [16384,256]
    float* out = (float*)d_out;

    // workspace layout (bytes):
    //   A2h : 8192*256*2   = 4 MB  @ 0
    //   B2h : 16384*256*2  = 8 MB  @ 4M
    //   rec : 8192*128*8   = 8 MB  @ 12M   ([token][chunk] packed u64)
    //   cnorm: 64 KB               @ 20M   (total ~20.06 MB)
    char* ws = (char*)d_ws;
    unsigned short* A2 = (unsigned short*)ws;
    unsigned short* B2 = (unsigned short*)(ws + (size_t)4 * 1024 * 1024);
    unsigned long long* rec = (unsigned long long*)(ws + (size_t)12 * 1024 * 1024);
    float* cnorm = (float*)(ws + (size_t)20 * 1024 * 1024);

    k_prep <<<4608, 256, 0, stream>>>(cb, z, B2, A2, cnorm);
    k_mfma <<<8192, 256, 0, stream>>>(A2, B2, cnorm, rec);
    k_pick <<<NTOK / 4, 256, 0, stream>>>(rec, z, cb, cnorm, out);
}